// Round 2
// baseline (697.675 us; speedup 1.0000x reference)
//
#include <hip/hip_runtime.h>
#include <hip/hip_bf16.h>
#include <stdint.h>

#define B_TOT 8192
#define F 64
#define D 256
#define NPAIR 2016
#define PITCH 264   // bf16 elems/LDS row: 256 + 8 pad -> 2-way bank aliasing only (free)
#define NBLK 1024   // 4 blocks/CU * 256 CUs
#define BPB 8       // batches per persistent block

typedef __bf16 bf16x8 __attribute__((ext_vector_type(8)));
typedef float f32x4 __attribute__((ext_vector_type(4)));

__device__ __forceinline__ unsigned short f2bf_rne(float f) {
    union { float f; unsigned int u; } x; x.f = f;
    unsigned int u = x.u;
    return (unsigned short)((u + 0x7FFFu + ((u >> 16) & 1u)) >> 16);
}

__global__ __launch_bounds__(256, 4)
void DotInteraction_kernel(const float* __restrict__ X, float* __restrict__ out)
{
    __shared__ unsigned short sX[F * PITCH];  // 33792 B -> 4 blocks/CU

    const int tid  = threadIdx.x;
    const int wave = tid >> 6;
    const int lane = tid & 63;
    const int r16  = lane & 15;
    const int quad = lane >> 4;

    const size_t b0 = (size_t)blockIdx.x * BPB;
    const float4* __restrict__ gp = (const float4*)(X + b0 * (F * D));

    // Prologue: load batch b0 into registers (16 float4 / thread = 64 VGPRs).
    float4 reg[16];
#pragma unroll
    for (int it = 0; it < 16; ++it)
        reg[it] = gp[it * 256 + tid];

    for (int bb = 0; bb < BPB; ++bb) {
        // ---- Convert current batch to bf16 + stage to LDS ----
#pragma unroll
        for (int it = 0; it < 16; ++it) {
            const int v   = it * 256 + tid;
            const int row = v >> 6;
            const int c4  = (v & 63) << 2;
            const float4 f = reg[it];
            ushort4 h;
            h.x = f2bf_rne(f.x);
            h.y = f2bf_rne(f.y);
            h.z = f2bf_rne(f.z);
            h.w = f2bf_rne(f.w);
            *(ushort4*)&sX[row * PITCH + c4] = h;
        }
        __syncthreads();

        // ---- Prefetch next batch while computing this one ----
        if (bb + 1 < BPB) {
            const float4* __restrict__ gn = gp + (size_t)(bb + 1) * (F * D / 4);
#pragma unroll
            for (int it = 0; it < 16; ++it)
                reg[it] = gn[it * 256 + tid];
        }

        // ---- Compute 10 upper-tri 16x16 tiles of X·X^T, round-robin over waves ----
        float* __restrict__ ob = out + (b0 + bb) * NPAIR;
        for (int t = wave; t < 10; t += 4) {
            int ti, tj;
            if      (t < 4) { ti = 0; tj = t; }
            else if (t < 7) { ti = 1; tj = t - 3; }
            else if (t < 9) { ti = 2; tj = t - 5; }
            else            { ti = 3; tj = 3; }

            f32x4 acc = {0.f, 0.f, 0.f, 0.f};
            const unsigned short* pa = &sX[(ti * 16 + r16) * PITCH + quad * 8];
            const unsigned short* pb = &sX[(tj * 16 + r16) * PITCH + quad * 8];
#pragma unroll
            for (int kk = 0; kk < 8; ++kk) {
                bf16x8 a   = *(const bf16x8*)(pa + kk * 32);  // ds_read_b128
                bf16x8 bfr = *(const bf16x8*)(pb + kk * 32);
                acc = __builtin_amdgcn_mfma_f32_16x16x32_bf16(a, bfr, acc, 0, 0, 0);
            }

            // C/D layout: col = lane&15, row = quad*4 + reg  [verified mapping]
            const int j = tj * 16 + r16;
#pragma unroll
            for (int r = 0; r < 4; ++r) {
                const int i = ti * 16 + quad * 4 + r;
                if (j > i) {
                    const int p = (i * (127 - i)) / 2 + (j - i - 1);
                    ob[p] = acc[r];
                }
            }
        }
        __syncthreads();  // protect LDS before next iteration's staging writes
    }
}

extern "C" void kernel_launch(void* const* d_in, const int* in_sizes, int n_in,
                              void* d_out, int out_size, void* d_ws, size_t ws_size,
                              hipStream_t stream) {
    const float* X = (const float*)d_in[0];
    float* out = (float*)d_out;
    DotInteraction_kernel<<<NBLK, 256, 0, stream>>>(X, out);
}